// Round 7
// baseline (1006.218 us; speedup 1.0000x reference)
//
#include <hip/hip_runtime.h>
#include <hip/hip_bf16.h>
#include <stdint.h>

typedef __bf16 bf16_t;
typedef __bf16 bf16x8 __attribute__((ext_vector_type(8)));
typedef float f32x4 __attribute__((ext_vector_type(4)));

constexpr int CC = 128, HH = 256, WW = 256;
constexpr int C4 = 512, K12 = 1536;
constexpr int AWP_ELEMS = 786432;        // [16 cb][512 o][96 kl] bf16
constexpr int LW2_ELEMS = 512 * 48;      // conv weights [c4][48] f32 (40 used)

// ---- prep ----
// awp[cb][o][kl], kl = 3*chan + g  <->  orig k = g*512 + cb*32 + chan
// lw2g[c4][48]: [r*8+0..4] = w5 row r; [r*8+5..7] = w3 row r-1 (r=1..3); [5] = w1 (r=0)
__global__ __launch_bounds__(256)
void prep(const float* __restrict__ wp, const float* __restrict__ w1,
          const float* __restrict__ w3, const float* __restrict__ w5,
          bf16_t* __restrict__ awp, float* __restrict__ lw2g)
{
    int t = blockIdx.x * 256 + threadIdx.x;
    if (t < AWP_ELEMS) {
        int kl = t % 96;
        int o  = (t / 96) & 511;
        int cb = t / (96 * 512);
        int chan = kl / 3, g = kl - chan * 3;
        awp[t] = (bf16_t)wp[o * K12 + g * C4 + cb * 32 + chan];
        return;
    }
    int u = t - AWP_ELEMS;
    if (u < LW2_ELEMS) {
        int c4 = u / 48, j = u - c4 * 48;
        int r = j >> 3, v = j & 7;
        float val = 0.f;
        if (j < 40) {
            if (v < 5)                 val = w5[c4 * 25 + r * 5 + v];
            else if (r >= 1 && r <= 3) val = w3[c4 * 9 + (r - 1) * 3 + (v - 5)];
            else if (r == 0 && v == 5) val = w1[c4];
        }
        lw2g[u] = val;
    }
}

__device__ __forceinline__ void gload4(const float* g, float* l) {
    __builtin_amdgcn_global_load_lds(
        (const __attribute__((address_space(1))) uint32_t*)g,
        (__attribute__((address_space(3))) uint32_t*)l, 4, 0, 0);
}
__device__ __forceinline__ uint16_t b16bits(float v) {
    return __builtin_bit_cast(uint16_t, (bf16_t)v);
}
__device__ __forceinline__ uint32_t pk2(float a, float b) {
    return (uint32_t)b16bits(a) | ((uint32_t)b16bits(b) << 16);
}

// ---- fused main: 1024 thr, 16 waves; waves 0-7 conv+GEMM, 8-15 pure GEMM ----
__global__ __launch_bounds__(1024, 4)
void wtconv_mfma(const float* __restrict__ x,
                 const bf16_t* __restrict__ awp,
                 const float* __restrict__ lw2g,
                 float* __restrict__ out)
{
    __shared__ __align__(16) float lx[32][5][140];   // 89,600 B (stride 140: 2-way banks)
    __shared__ __align__(16) char  BtB[2][128 * 256];// 65,536 B feats^T dbuf, swizzled
    __shared__ __align__(16) float lw2s[32][48];     //  6,144 B conv weights

    const int tid = threadIdx.x;
    const int lane = tid & 63;
    const int wid = __builtin_amdgcn_readfirstlane(tid >> 6);
    const int nb = blockIdx.x;                 // XCD swizzle: XCD owns one batch
    const int m = (nb & 7) * 128 + (nb >> 3);
    const int b = m >> 7, i = m & 127;
    const int wm = wid & 7, wn = wid >> 3;     // 8 M-waves x 2 N-waves (GEMM)
    const int lrow = lane & 15, lkh = lane >> 4;
    const float* xb = x + (size_t)b * CC * HH * WW;

    // zero lx once (halo cols 0,1,130..139 + OOB rows stay 0 forever)
    for (int e = tid; e < 32 * 5 * 140 / 4; e += 1024)
        ((f32x4*)lx)[e] = (f32x4){0.f, 0.f, 0.f, 0.f};
    __syncthreads();

    f32x4 acc[4][4];
#pragma unroll
    for (int a = 0; a < 4; ++a)
#pragma unroll
        for (int c = 0; c < 4; ++c) acc[a][c] = (f32x4){0.f, 0.f, 0.f, 0.f};

    // each conv wave stages ONLY its own 4 channels (race-free single-buffer lx/lw)
    auto issue_own = [&](int kk) {
        const int q4 = kk >> 2, qy = q4 >> 1, qx = q4 & 1;
        const int bcb = (kk & 3) * 32;
#pragma unroll
        for (int cl = 0; cl < 4; ++cl) {
            const int chan = wid * 4 + cl;
#pragma unroll
            for (int r = 0; r < 5; ++r) {
                const int ri = i + r - 2;
                if ((unsigned)ri < 128u) {
                    const float* s = xb + (((size_t)(bcb + chan)) << 16)
                                   + (2 * ri + qy) * WW + qx;
                    gload4(s + 2 * lane,       &lx[chan][r][2]);
                    gload4(s + 128 + 2 * lane, &lx[chan][r][66]);
                }
            }
        }
        const float* wsrc = lw2g + kk * 1536 + wid * 192;   // 4 chans x 48
        float* wdst = &lw2s[wid * 4][0];
#pragma unroll
        for (int t = 0; t < 3; ++t)
            gload4(wsrc + t * 64 + lane, wdst + t * 64);
    };

    if (wid < 8) issue_own(0);

    const int chan = (tid >> 4) & 31;    // conv mapping (waves 0-7): tid 0..511
    const int oct = tid & 15;
    const int px0 = oct * 8;

#pragma unroll 1
    for (int k = 0; k <= 16; ++k) {
        __syncthreads();   // vmcnt+lgkm drain: lx/lw(k) ready; GEMM(k-2) done -> Bt[k&1] free

        if (wid < 8 && k < 16) {
            // ---- conv(k): 1 chan x 8 px per thread ----
            const float* wr = &lw2s[chan][0];
            float f5[8] = {0,0,0,0,0,0,0,0}, f3[8] = {0,0,0,0,0,0,0,0}, f1[8];
            float w1v = 0.f;
#pragma unroll
            for (int r = 0; r < 5; ++r) {
                f32x4 wA = *(const f32x4*)(wr + r * 8);
                f32x4 wB = *(const f32x4*)(wr + r * 8 + 4);
                f32x4 v0 = *(const f32x4*)&lx[chan][r][px0];
                f32x4 v1 = *(const f32x4*)&lx[chan][r][px0 + 4];
                f32x4 v2 = *(const f32x4*)&lx[chan][r][px0 + 8];
                float c[12] = {v0[0],v0[1],v0[2],v0[3], v1[0],v1[1],v1[2],v1[3],
                               v2[0],v2[1],v2[2],v2[3]};
                if (r == 0) w1v = wB[1];
#pragma unroll
                for (int d = 0; d < 8; ++d)
                    f5[d] += wA[0]*c[d] + wA[1]*c[d+1] + wA[2]*c[d+2]
                           + wA[3]*c[d+3] + wB[0]*c[d+4];
                if (r >= 1 && r <= 3) {
#pragma unroll
                    for (int d = 0; d < 8; ++d)
                        f3[d] += wB[1]*c[d+1] + wB[2]*c[d+2] + wB[3]*c[d+3];
                }
                if (r == 2) {
#pragma unroll
                    for (int d = 0; d < 8; ++d) f1[d] = w1v * c[d + 2];
                }
            }
            // Bt[k&1] writes: kl = 3*chan + {0,1,2}; b32+b16 per px (alignment via parity)
            char* btb = BtB[k & 1];
            const int odd = chan & 1;
            const int b32off = 6 * chan + 2 * odd;       // even: f1,f3 | odd: f3,f5
            const int b16off = 6 * chan + 4 - 4 * odd;   // even: f5    | odd: f1
#pragma unroll
            for (int d = 0; d < 8; ++d) {
                const int row = px0 + d;
                const int sw = (((row >> 1) ^ (row >> 2)) & 7) << 4;
                char* base = btb + row * 256;
                float lo = odd ? f3[d] : f1[d];
                float hi = odd ? f5[d] : f3[d];
                float sv = odd ? f1[d] : f5[d];
                *(uint32_t*)(base + (b32off ^ sw)) = pk2(lo, hi);
                *(uint16_t*)(base + (b16off ^ sw)) = b16bits(sv);
            }
            if (k < 15) issue_own(k + 1);   // prefetch next tile (own chans only)
        }

        if (k > 0) {
            // ---- GEMM(k-1): B from Bt[(k-1)&1], A direct from L2-resident awp ----
            const int prev = k - 1;
            const char* btb = BtB[prev & 1];
            const bf16_t* abase = awp + (size_t)prev * (512 * 96);
#pragma unroll
            for (int s = 0; s < 3; ++s) {
                bf16x8 bfrag[4];
#pragma unroll
                for (int nf = 0; nf < 4; ++nf) {
                    const int row = wn * 64 + nf * 16 + lrow;
                    const int sw = (((row >> 1) ^ (row >> 2)) & 7) << 4;
                    bfrag[nf] = *(const bf16x8*)(btb + row * 256
                                                 + ((s * 64 + lkh * 16) ^ sw));
                }
#pragma unroll
                for (int mf = 0; mf < 4; ++mf) {
                    const int o = wm * 64 + mf * 16 + lrow;
                    bf16x8 af = *(const bf16x8*)(abase + o * 96 + s * 32 + lkh * 8);
#pragma unroll
                    for (int nf = 0; nf < 4; ++nf)
                        acc[mf][nf] = __builtin_amdgcn_mfma_f32_16x16x32_bf16(
                            af, bfrag[nf], acc[mf][nf], 0, 0, 0);
                }
            }
        }
    }

    // ---- IDWT scatter epilogue: o = wm*64+..., quadrant = o>>7 ----
    const int oy = 2 * i + (wm >> 2);
    const int ox = (wm >> 1) & 1;
#pragma unroll
    for (int mf = 0; mf < 4; ++mf)
#pragma unroll
        for (int nf = 0; nf < 4; ++nf)
#pragma unroll
            for (int r = 0; r < 4; ++r) {
                const int bco = (wm & 1) * 64 + mf * 16 + lkh * 4 + r;
                const int px  = wn * 64 + nf * 16 + lrow;
                out[((size_t)(b * CC + bco) * HH + oy) * WW + 2 * px + ox]
                    = acc[mf][nf][r];
            }
}

extern "C" void kernel_launch(void* const* d_in, const int* in_sizes, int n_in,
                              void* d_out, int out_size, void* d_ws, size_t ws_size,
                              hipStream_t stream) {
    const float* x  = (const float*)d_in[0];
    const float* w1 = (const float*)d_in[1];
    const float* w3 = (const float*)d_in[2];
    const float* w5 = (const float*)d_in[3];
    const float* wp = (const float*)d_in[4];
    float* out = (float*)d_out;
    bf16_t* awp = (bf16_t*)d_ws;                                   // 1.50 MB
    float* lw2g = (float*)((char*)d_ws + (size_t)AWP_ELEMS * 2);   // 96 KB

    int prep_total = AWP_ELEMS + LW2_ELEMS;
    hipLaunchKernelGGL(prep, dim3((prep_total + 255) / 256), dim3(256), 0, stream,
                       wp, w1, w3, w5, awp, lw2g);
    hipLaunchKernelGGL(wtconv_mfma, dim3(1024), dim3(1024), 0, stream,
                       x, awp, lw2g, out);
}

// Round 8
// 514.769 us; speedup vs baseline: 1.9547x; 1.9547x over previous
//
#include <hip/hip_runtime.h>
#include <hip/hip_bf16.h>
#include <stdint.h>

typedef __bf16 bf16_t;
typedef __bf16 bf16x8 __attribute__((ext_vector_type(8)));
typedef float f32x4 __attribute__((ext_vector_type(4)));

constexpr int CC = 128, HH = 256, WW = 256;
constexpr int C4 = 512, K12 = 1536;
constexpr int AWP_ELEMS = 786432;        // [g*16+cb][512 o][32 kk] bf16
constexpr int LW2_ELEMS = 512 * 40;      // conv weights [c4][5][8] f32

// ---- prep: pack w_proj -> bf16 tiled; conv w -> [c4][5][8] ----
// row r slots: [0..4] = w5 row r; [5..7] = w3 row r-1 (rows 1..3); [0][5] = w1.
__global__ __launch_bounds__(256)
void prep(const float* __restrict__ wp, const float* __restrict__ w1,
          const float* __restrict__ w3, const float* __restrict__ w5,
          bf16_t* __restrict__ awp, float* __restrict__ lw2g)
{
    int t = blockIdx.x * 256 + threadIdx.x;
    if (t < AWP_ELEMS) {
        int kk = t & 31, o = (t >> 5) & 511, t2 = t >> 14;
        int g = t2 >> 4, cb = t2 & 15;
        awp[t] = (bf16_t)wp[o * K12 + g * C4 + cb * 32 + kk];
        return;
    }
    int u = t - AWP_ELEMS;
    if (u < LW2_ELEMS) {
        int c4 = u / 40, j = u - c4 * 40;
        int r = j >> 3, v = j & 7;
        float val = 0.f;
        if (v < 5)                 val = w5[c4 * 25 + r * 5 + v];
        else if (r >= 1 && r <= 3) val = w3[c4 * 9 + (r - 1) * 3 + (v - 5)];
        else if (r == 0 && v == 5) val = w1[c4];
        lw2g[u] = val;
    }
}

__device__ __forceinline__ void gload4(const float* g, float* l) {
    __builtin_amdgcn_global_load_lds(
        (const __attribute__((address_space(1))) uint32_t*)g,
        (__attribute__((address_space(3))) uint32_t*)l, 4, 0, 0);
}
__device__ __forceinline__ uint16_t b16bits(float v) {
    return __builtin_bit_cast(uint16_t, (bf16_t)v);
}

// Bt swizzle: row stride 256 B; 16B chunk XOR by f(row) = ((row>>1)^(row>>2))&7.
__device__ __forceinline__ int bt_off(int row, int colbyte) {
    int f = ((row >> 1) ^ (row >> 2)) & 7;
    return row * 256 + (colbyte ^ (f << 4));
}

// ---- fused main: 1024 thr, 16 waves, all conv+GEMM; Bt dbuf, 1 barrier/iter ----
__global__ __launch_bounds__(1024, 4)
void wtconv_mfma(const float* __restrict__ x,
                 const bf16_t* __restrict__ awp,
                 const float* __restrict__ lw2g,
                 float* __restrict__ out)
{
    __shared__ __align__(16) float lx[32][5][136];    // 87,040 B; borders stay 0
    __shared__ __align__(16) char  BtB[2][128 * 256]; // 65,536 B feats^T dbuf
    __shared__ __align__(16) float lw2s[32][40];      //  5,120 B conv weights

    const int tid = threadIdx.x;
    const int lane = tid & 63;
    const int wid = __builtin_amdgcn_readfirstlane(tid >> 6);  // scalar wave id
    const int nb = blockIdx.x;                 // XCD swizzle: XCD owns one batch
    const int m = (nb & 7) * 128 + (nb >> 3);
    const int b = m >> 7, i = m & 127;
    const int wm = wid & 7, wn = wid >> 3;     // 8 M-waves x 2 N-waves (GEMM)
    const int lrow = lane & 15, lkh = lane >> 4;
    const float* xb = x + (size_t)b * CC * HH * WW;

    // zero lx once (halo cols 0,1,130..135 + OOB rows stay 0 forever)
    for (int e = tid; e < 32 * 5 * 136 / 4; e += 1024)
        ((f32x4*)lx)[e] = (f32x4){0.f, 0.f, 0.f, 0.f};
    __syncthreads();

    f32x4 acc[4][4];
#pragma unroll
    for (int a = 0; a < 4; ++a)
#pragma unroll
        for (int c = 0; c < 4; ++c) acc[a][c] = (f32x4){0.f, 0.f, 0.f, 0.f};

    // each wave stages ONLY its own 2 channels (race-free single-buffer lx/lw)
    auto issue_own = [&](int kk) {
        const int q4 = kk >> 2, qy = q4 >> 1, qx = q4 & 1;
        const int bcb = (kk & 3) * 32;
#pragma unroll
        for (int cl = 0; cl < 2; ++cl) {
            const int chan = wid * 2 + cl;
#pragma unroll
            for (int r = 0; r < 5; ++r) {
                const int ri = i + r - 2;
                if ((unsigned)ri < 128u) {
                    const float* s = xb + (((size_t)(bcb + chan)) << 16)
                                   + (2 * ri + qy) * WW + qx;
                    gload4(s + 2 * lane,       &lx[chan][r][2]);
                    gload4(s + 128 + 2 * lane, &lx[chan][r][66]);
                }
            }
        }
        // 2 chans x 40 weights = 80 floats contiguous at lw2s[2*wid]
        const float* wsrc = lw2g + kk * 1280 + wid * 80;
        float* wdst = &lw2s[wid * 2][0];
        gload4(wsrc + lane, wdst);
        if (lane < 16) gload4(wsrc + 64 + lane, wdst + 64);
    };

    issue_own(0);

    const int chan = tid >> 5;           // 0..31 (lanes 0-31 -> 2*wid, 32-63 -> 2*wid+1)
    const int pxq = tid & 31;
    const int px0 = pxq * 4;

#pragma unroll 1
    for (int k = 0; k <= 16; ++k) {
        __syncthreads();   // vmcnt+lgkm drain: lx/lw(k) landed; Bt[k&1] free (reads at k-1 done)

        if (k < 16) {
            // ---- conv(k): 1 chan x 4 px per thread (register-light) ----
            const float* wr = &lw2s[chan][0];
            float f5[4] = {0.f,0.f,0.f,0.f}, f3[4] = {0.f,0.f,0.f,0.f}, f1[4];
            float w1v = 0.f;
#pragma unroll
            for (int r = 0; r < 5; ++r) {
                f32x4 wA = *(const f32x4*)(wr + r * 8);
                f32x4 wB = *(const f32x4*)(wr + r * 8 + 4);
                f32x4 a  = *(const f32x4*)&lx[chan][r][px0];
                f32x4 bv = *(const f32x4*)&lx[chan][r][px0 + 4];
                float c[8] = {a[0],a[1],a[2],a[3],bv[0],bv[1],bv[2],bv[3]};
                if (r == 0) w1v = wB[1];
#pragma unroll
                for (int d = 0; d < 4; ++d)
                    f5[d] += wA[0]*c[d] + wA[1]*c[d+1] + wA[2]*c[d+2]
                           + wA[3]*c[d+3] + wB[0]*c[d+4];
                if (r >= 1 && r <= 3) {
#pragma unroll
                    for (int d = 0; d < 4; ++d)
                        f3[d] += wB[1]*c[d+1] + wB[2]*c[d+2] + wB[3]*c[d+3];
                }
                if (r == 2) {
#pragma unroll
                    for (int d = 0; d < 4; ++d) f1[d] = w1v * c[d + 2];
                }
            }
            char* btb = BtB[k & 1];
            const int cby = chan * 2;
#pragma unroll
            for (int d = 0; d < 4; ++d) {
                const int row = px0 + d;
                const int sw = (((row >> 1) ^ (row >> 2)) & 7) << 4;
                char* base = btb + row * 256;
                *(uint16_t*)(base + ((cby) ^ sw))        = b16bits(f1[d]);
                *(uint16_t*)(base + ((64 + cby) ^ sw))   = b16bits(f3[d]);
                *(uint16_t*)(base + ((128 + cby) ^ sw))  = b16bits(f5[d]);
            }
            if (k < 15) issue_own(k + 1);   // prefetch next tile (own chans only)
        }

        if (k > 0) {
            // ---- GEMM(k-1): B from Bt[(k-1)&1], A direct from L2-resident awp ----
            const int prev = k - 1;
            const char* btb = BtB[prev & 1];
#pragma unroll
            for (int s = 0; s < 3; ++s) {
                bf16x8 bfrag[4];
#pragma unroll
                for (int nf = 0; nf < 4; ++nf) {
                    const int row = wn * 64 + nf * 16 + lrow;
                    const int sw = (((row >> 1) ^ (row >> 2)) & 7) << 4;
                    bfrag[nf] = *(const bf16x8*)(btb + row * 256
                                                 + ((s * 64 + lkh * 16) ^ sw));
                }
                const bf16_t* abase = awp + (size_t)(s * 16 + prev) * (512 * 32);
#pragma unroll
                for (int mf = 0; mf < 4; ++mf) {
                    const int o = wm * 64 + mf * 16 + lrow;
                    bf16x8 af = *(const bf16x8*)(abase + o * 32 + lkh * 8);
#pragma unroll
                    for (int nf = 0; nf < 4; ++nf)
                        acc[mf][nf] = __builtin_amdgcn_mfma_f32_16x16x32_bf16(
                            af, bfrag[nf], acc[mf][nf], 0, 0, 0);
                }
            }
        }
    }

    // ---- IDWT scatter epilogue ----
    const int oy = 2 * i + (wm >> 2);
    const int ox = (wm >> 1) & 1;
#pragma unroll
    for (int mf = 0; mf < 4; ++mf)
#pragma unroll
        for (int nf = 0; nf < 4; ++nf)
#pragma unroll
            for (int r = 0; r < 4; ++r) {
                const int bco = (wm & 1) * 64 + mf * 16 + lkh * 4 + r;
                const int px  = wn * 64 + nf * 16 + lrow;
                out[((size_t)(b * CC + bco) * HH + oy) * WW + 2 * px + ox]
                    = acc[mf][nf][r];
            }
}

extern "C" void kernel_launch(void* const* d_in, const int* in_sizes, int n_in,
                              void* d_out, int out_size, void* d_ws, size_t ws_size,
                              hipStream_t stream) {
    const float* x  = (const float*)d_in[0];
    const float* w1 = (const float*)d_in[1];
    const float* w3 = (const float*)d_in[2];
    const float* w5 = (const float*)d_in[3];
    const float* wp = (const float*)d_in[4];
    float* out = (float*)d_out;
    bf16_t* awp = (bf16_t*)d_ws;                                   // 1.50 MB
    float* lw2g = (float*)((char*)d_ws + (size_t)AWP_ELEMS * 2);   // 80 KB

    int prep_total = AWP_ELEMS + LW2_ELEMS;
    hipLaunchKernelGGL(prep, dim3((prep_total + 255) / 256), dim3(256), 0, stream,
                       wp, w1, w3, w5, awp, lw2g);
    hipLaunchKernelGGL(wtconv_mfma, dim3(1024), dim3(1024), 0, stream,
                       x, awp, lw2g, out);
}